// Round 5
// baseline (726.143 us; speedup 1.0000x reference)
//
#include <hip/hip_runtime.h>

// GNN encoder layer: LN -> mean-aggregate over edges -> SAGEConv -> relu -> +residual
// Pipeline (all on `stream`, graph-capture safe):
//  1. ln_kernel      : h = LN(x)*gamma+beta -> bf16 into A_cat[:,512:1024], fp8 copy into h8
//  2. wconv_kernel   : W_cat[j,0:512]=bf16(W_l[j,:]), W_cat[j,512:1024]=bf16(W_r[j,:])
//  3. zero + hist    : cnt[d] = in-degree
//  4. scan1/2/3      : row_start = exclusive_scan(cnt); cur(=cnt) = row_start
//  5. scatter_kernel : sorted_src = src indices grouped by dst (CSR)
//  6. agg_kernel     : mean of fp8 h rows (fp32 accum) -> bf16 into A_cat[:,0:512]
//  7. gemm_kernel    : out = relu(A_cat @ W_cat^T + b_l) + residual
//     Round-6/7 (barrier-free GEMM; round-6 was an infra flake, resubmitted
//     unchanged): rounds 2-5 proved ~190us is invariant across ALL LDS-staged
//     barrier-per-K-tile schedules (depth 1/2/3, conflicts or not, drain or
//     counted) -- lockstep barrier amplifies any load-return tail to all 512
//     threads. New structure: B-panel (BN=64 x K=1024 = 128KB) resident in LDS,
//     loaded ONCE (single barrier); each wave privately owns 64 A-rows and
//     streams A global->VGPR with distance-2 register prefetch. ZERO barriers
//     and zero LDS writes in the K-loop -> waves run free, TLP hides latency.
//     - XCD swizzle: 8 N-sibling blocks of one 1MB A-stripe land on one XCD's L2.

#define D_DIM 512

typedef __bf16 bf16x8 __attribute__((ext_vector_type(8)));
typedef float f32x4 __attribute__((ext_vector_type(4)));
typedef float f32x2 __attribute__((ext_vector_type(2)));

__device__ __forceinline__ unsigned short f2bf(float f) {
  unsigned u = __float_as_uint(f);
  u += 0x7fffu + ((u >> 16) & 1u);   // RNE
  return (unsigned short)(u >> 16);
}
__device__ __forceinline__ float bflo(unsigned u) { return __uint_as_float(u << 16); }
__device__ __forceinline__ float bfhi(unsigned u) { return __uint_as_float(u & 0xffff0000u); }
__device__ __forceinline__ unsigned packbf2(float lo, float hi) {
  return (unsigned)f2bf(lo) | ((unsigned)f2bf(hi) << 16);
}

// ---------------- LayerNorm: one wave per row, 8 floats/lane ----------------
__global__ void ln_kernel(const float* __restrict__ x, const float* __restrict__ gamma,
                          const float* __restrict__ beta, unsigned short* __restrict__ Acat,
                          unsigned char* __restrict__ h8, int n, int use_fp8) {
  int lane = threadIdx.x & 63;
  int row = blockIdx.x * 4 + (threadIdx.x >> 6);
  if (row >= n) return;
  const float* xr = x + (size_t)row * D_DIM + lane * 8;
  float4 a = *(const float4*)xr;
  float4 b = *(const float4*)(xr + 4);
  float sum = a.x + a.y + a.z + a.w + b.x + b.y + b.z + b.w;
  float sq = a.x * a.x + a.y * a.y + a.z * a.z + a.w * a.w +
             b.x * b.x + b.y * b.y + b.z * b.z + b.w * b.w;
#pragma unroll
  for (int m = 1; m < 64; m <<= 1) {
    sum += __shfl_xor(sum, m, 64);
    sq  += __shfl_xor(sq, m, 64);
  }
  float mu = sum * (1.0f / D_DIM);
  float var = sq * (1.0f / D_DIM) - mu * mu;
  float rs = rsqrtf(var + 1e-5f);
  const float* gp = gamma + lane * 8;
  const float* bp = beta + lane * 8;
  float4 g0 = *(const float4*)gp, g1 = *(const float4*)(gp + 4);
  float4 e0 = *(const float4*)bp, e1 = *(const float4*)(bp + 4);
  float h0 = (a.x - mu) * rs * g0.x + e0.x;
  float h1 = (a.y - mu) * rs * g0.y + e0.y;
  float h2 = (a.z - mu) * rs * g0.z + e0.z;
  float h3 = (a.w - mu) * rs * g0.w + e0.w;
  float h4 = (b.x - mu) * rs * g1.x + e1.x;
  float h5 = (b.y - mu) * rs * g1.y + e1.y;
  float h6 = (b.z - mu) * rs * g1.z + e1.z;
  float h7 = (b.w - mu) * rs * g1.w + e1.w;
  uint4 st = { packbf2(h0, h1), packbf2(h2, h3), packbf2(h4, h5), packbf2(h6, h7) };
  *(uint4*)(Acat + (size_t)row * 1024 + 512 + lane * 8) = st;
  if (use_fp8) {
    int p0 = __builtin_amdgcn_cvt_pk_fp8_f32(h0, h1, 0, false);
    p0 = __builtin_amdgcn_cvt_pk_fp8_f32(h2, h3, p0, true);
    int p1 = __builtin_amdgcn_cvt_pk_fp8_f32(h4, h5, 0, false);
    p1 = __builtin_amdgcn_cvt_pk_fp8_f32(h6, h7, p1, true);
    uint2 st2 = { (unsigned)p0, (unsigned)p1 };
    *(uint2*)(h8 + (size_t)row * 512 + lane * 8) = st2;
  }
}

// ---------------- W concat + bf16 convert ----------------
__global__ void wconv_kernel(const float* __restrict__ Wl, const float* __restrict__ Wr,
                             unsigned short* __restrict__ Wcat) {
  int id = blockIdx.x * 256 + threadIdx.x;  // 0 .. 512*512-1
  int j = id >> 9, k = id & 511;
  Wcat[(size_t)j * 1024 + k] = f2bf(Wl[id]);
  Wcat[(size_t)j * 1024 + 512 + k] = f2bf(Wr[id]);
}

// ---------------- CSR build ----------------
__global__ void zero_kernel(int* __restrict__ p, int n) {
  int i = blockIdx.x * 256 + threadIdx.x;
  if (i < n) p[i] = 0;
}

__global__ void hist_kernel(const int* __restrict__ dst, int nE, int* __restrict__ cnt) {
  int e = blockIdx.x * 256 + threadIdx.x;
  if (e < nE) atomicAdd(&cnt[dst[e]], 1);
}

__global__ void scan1_kernel(const int* __restrict__ cnt, int n,
                             int* __restrict__ excl, int* __restrict__ bsums) {
  __shared__ int wsum[16];
  int gid = blockIdx.x * 1024 + threadIdx.x;
  int lane = threadIdx.x & 63, wave = threadIdx.x >> 6;
  int v = (gid < n) ? cnt[gid] : 0;
  int s = v;
#pragma unroll
  for (int d = 1; d < 64; d <<= 1) {
    int t = __shfl_up(s, d, 64);
    if (lane >= d) s += t;
  }
  if (lane == 63) wsum[wave] = s;
  __syncthreads();
  if (wave == 0) {
    int ws = (lane < 16) ? wsum[lane] : 0;
#pragma unroll
    for (int d = 1; d < 16; d <<= 1) {
      int t = __shfl_up(ws, d, 64);
      if (lane >= d) ws += t;
    }
    if (lane < 16) wsum[lane] = ws;
  }
  __syncthreads();
  int incl = s + ((wave > 0) ? wsum[wave - 1] : 0);
  if (gid < n) excl[gid] = incl - v;
  if (threadIdx.x == 1023) bsums[blockIdx.x] = incl;
}

__global__ void scan2_kernel(int* __restrict__ bsums, int nb) {
  int lane = threadIdx.x;  // 64 threads, nb <= 64
  int v = (lane < nb) ? bsums[lane] : 0;
  int s = v;
#pragma unroll
  for (int d = 1; d < 64; d <<= 1) {
    int t = __shfl_up(s, d, 64);
    if (lane >= d) s += t;
  }
  if (lane < nb) bsums[lane] = s - v;  // exclusive
}

__global__ void scan3_kernel(int* __restrict__ rowst, int* __restrict__ cur,
                             const int* __restrict__ bsums, int n, int nE) {
  int gid = blockIdx.x * 1024 + threadIdx.x;
  if (gid < n) {
    int r = rowst[gid] + bsums[blockIdx.x];
    rowst[gid] = r;
    cur[gid] = r;
  }
  if (gid == 0) rowst[n] = nE;
}

__global__ void scatter_kernel(const int* __restrict__ src, const int* __restrict__ dst,
                               int nE, int* __restrict__ cur, int* __restrict__ sorted_src) {
  int e = blockIdx.x * 256 + threadIdx.x;
  if (e < nE) {
    int p = atomicAdd(&cur[dst[e]], 1);
    sorted_src[p] = src[e];
  }
}

// ---------------- aggregation: one wave per dst node ----------------
__device__ __forceinline__ void acc_bf(float* acc, uint4 r) {
  acc[0] += bflo(r.x); acc[1] += bfhi(r.x);
  acc[2] += bflo(r.y); acc[3] += bfhi(r.y);
  acc[4] += bflo(r.z); acc[5] += bfhi(r.z);
  acc[6] += bflo(r.w); acc[7] += bfhi(r.w);
}

__device__ __forceinline__ void acc_f8(float* acc, uint2 r) {
  f32x2 a = __builtin_amdgcn_cvt_pk_f32_fp8(r.x, false);
  f32x2 b = __builtin_amdgcn_cvt_pk_f32_fp8(r.x, true);
  f32x2 c = __builtin_amdgcn_cvt_pk_f32_fp8(r.y, false);
  f32x2 d = __builtin_amdgcn_cvt_pk_f32_fp8(r.y, true);
  acc[0] += a.x; acc[1] += a.y; acc[2] += b.x; acc[3] += b.y;
  acc[4] += c.x; acc[5] += c.y; acc[6] += d.x; acc[7] += d.y;
}

__global__ void agg_kernel(unsigned short* __restrict__ Acat,
                           const unsigned char* __restrict__ h8,
                           const int* __restrict__ rowst,
                           const int* __restrict__ sorted_src, int n, int use_fp8) {
  int lane = threadIdx.x & 63;
  int node = blockIdx.x * 4 + (threadIdx.x >> 6);
  if (node >= n) return;
  int s0 = rowst[node], s1 = rowst[node + 1];
  float acc[8] = {0.f, 0.f, 0.f, 0.f, 0.f, 0.f, 0.f, 0.f};
  if (use_fp8) {
    const unsigned char* hb = h8 + lane * 8;
    int e = s0;
    for (; e + 3 < s1; e += 4) {
      int i0 = sorted_src[e], i1 = sorted_src[e + 1];
      int i2 = sorted_src[e + 2], i3 = sorted_src[e + 3];
      uint2 r0 = *(const uint2*)(hb + (size_t)i0 * 512);
      uint2 r1 = *(const uint2*)(hb + (size_t)i1 * 512);
      uint2 r2 = *(const uint2*)(hb + (size_t)i2 * 512);
      uint2 r3 = *(const uint2*)(hb + (size_t)i3 * 512);
      acc_f8(acc, r0); acc_f8(acc, r1); acc_f8(acc, r2); acc_f8(acc, r3);
    }
    for (; e < s1; ++e) {
      uint2 r0 = *(const uint2*)(hb + (size_t)sorted_src[e] * 512);
      acc_f8(acc, r0);
    }
  } else {
    const unsigned short* hbase = Acat + 512 + lane * 8;
    int e = s0;
    for (; e + 3 < s1; e += 4) {
      int i0 = sorted_src[e], i1 = sorted_src[e + 1];
      int i2 = sorted_src[e + 2], i3 = sorted_src[e + 3];
      uint4 r0 = *(const uint4*)(hbase + (size_t)i0 * 1024);
      uint4 r1 = *(const uint4*)(hbase + (size_t)i1 * 1024);
      uint4 r2 = *(const uint4*)(hbase + (size_t)i2 * 1024);
      uint4 r3 = *(const uint4*)(hbase + (size_t)i3 * 1024);
      acc_bf(acc, r0); acc_bf(acc, r1); acc_bf(acc, r2); acc_bf(acc, r3);
    }
    for (; e < s1; ++e) {
      uint4 r0 = *(const uint4*)(hbase + (size_t)sorted_src[e] * 1024);
      acc_bf(acc, r0);
    }
  }
  int deg = s1 - s0;
  float sc = (deg > 0) ? (1.0f / (float)deg) : 0.0f;
  uint4 st = { packbf2(acc[0] * sc, acc[1] * sc), packbf2(acc[2] * sc, acc[3] * sc),
               packbf2(acc[4] * sc, acc[5] * sc), packbf2(acc[6] * sc, acc[7] * sc) };
  *(uint4*)(Acat + (size_t)node * 1024 + lane * 8) = st;
}

// ---------------- GEMM: [Mpad x 1024] @ [512 x 1024]^T, barrier-free ----------------
// BM=512 (8 waves x 64 private rows), BN=64. B-panel 64x1024 bf16 = 128KB lives
// in LDS for the whole kernel (staged once, one barrier). K-loop: A streamed
// global->VGPR per wave (distance-2 register prefetch), B read from LDS with the
// XOR-chunk swizzle (2-way = free). NO barriers, NO LDS writes in the loop.
__device__ __forceinline__ void async16(const unsigned short* g, char* lds) {
  __builtin_amdgcn_global_load_lds((const __attribute__((address_space(1))) void*)g,
                                   (__attribute__((address_space(3))) void*)lds, 16, 0, 0);
}

__global__ __launch_bounds__(512, 2) void gemm_kernel(
    const unsigned short* __restrict__ A,  // [Mpad][1024] bf16 (mean | h)
    const unsigned short* __restrict__ B,  // [512][1024]  bf16 (W_l | W_r), row = out col
    const float* __restrict__ bias,        // b_l [512]
    const float* __restrict__ residual,    // x [M][512]
    float* __restrict__ out, int M, int Mtiles) {
  __shared__ unsigned short sB[64 * 1024];  // 128 KB: whole B panel, swizzled
  const int K = 1024;
  int t = threadIdx.x;
  int lane = t & 63, wv = t >> 6;
  int quad = lane >> 4, l16 = lane & 15;
  // XCD swizzle: the 8 nb-siblings of one A-stripe are blocks b, b+8, .., b+56
  // (same b&7 -> same XCD under round-robin) -> 1MB A-stripe stays in that L2.
  int b = blockIdx.x;
  int mb = (b >> 6) * 8 + (b & 7);
  int nb = (b >> 3) & 7;
  if (mb >= Mtiles) return;
  int mBase = mb * 512, nBase = nb * 64;

  // ---- stage B panel once (swizzled): LDS slot (row, d) holds global chunk
  // d ^ (row&7) (16B chunks, 128 per row). Linear DMA dest (rule #21): wave wv,
  // instr i -> bytes [wv*16384 + i*1024 + lane*16]; that slot is row wv*8+(i>>1),
  // chunk d=(i&1)*64+lane, so the per-lane SOURCE chunk is (i&1)*64 + (lane^s),
  // s=(i>>1)&7. XOR within 128B-aligned groups keeps 64B-coalescing intact.
  {
    char* ldsBase = (char*)&sB[0] + wv * 16384;
    const unsigned short* gB = B + (size_t)(nBase + wv * 8) * K;
#pragma unroll
    for (int i = 0; i < 16; ++i) {
      int s = (i >> 1) & 7;
      const unsigned short* g = gB + (size_t)(i >> 1) * K + (i & 1) * 512 + ((lane ^ s) * 8);
      async16(g, ldsBase + i * 1024);
    }
  }
  asm volatile("s_waitcnt vmcnt(0)\n\ts_barrier" ::: "memory");
  // ---- from here on: no barriers, no LDS writes; waves run independently ----

  // wave's private A rows: mBase + wv*64 + i*16 + l16 (i=0..3)
  const unsigned short* gA = A + (size_t)(mBase + wv * 64 + l16) * K + quad * 8;
  f32x4 acc[4][4] = {};
  int swz = l16 & 7;

  bf16x8 a0[4], a1[4];
#pragma unroll
  for (int i = 0; i < 4; ++i) a0[i] = *(const bf16x8*)(gA + (size_t)i * 16 * K);
#pragma unroll
  for (int i = 0; i < 4; ++i) a1[i] = *(const bf16x8*)(gA + (size_t)i * 16 * K + 32);

  for (int kt = 0; kt < 32; kt += 2) {
    // ---- K-step kt (A in a0) ----
    bf16x8 bfr[4];
#pragma unroll
    for (int j = 0; j < 4; ++j) {
      int pc = (kt * 4 + quad) ^ swz;
      bfr[j] = *(const bf16x8*)(&sB[(j * 16 + l16) * 1024 + pc * 8]);
    }
    __builtin_amdgcn_s_setprio(1);
#pragma unroll
    for (int i = 0; i < 4; ++i)
#pragma unroll
      for (int j = 0; j < 4; ++j)
        acc[i][j] = __builtin_amdgcn_mfma_f32_16x16x32_bf16(a0[i], bfr[j], acc[i][j], 0, 0, 0);
    __builtin_amdgcn_s_setprio(0);
    if (kt + 2 < 32) {
#pragma unroll
      for (int i = 0; i < 4; ++i)
        a0[i] = *(const bf16x8*)(gA + (size_t)i * 16 * K + (kt + 2) * 32);
    }
    // ---- K-step kt+1 (A in a1) ----
    bf16x8 bfr2[4];
#pragma unroll
    for (int j = 0; j < 4; ++j) {
      int pc = ((kt + 1) * 4 + quad) ^ swz;
      bfr2[j] = *(const bf16x8*)(&sB[(j * 16 + l16) * 1024 + pc * 8]);
    }
    __builtin_amdgcn_s_setprio(1);
#pragma unroll
    for (int i = 0; i < 4; ++i)
#pragma unroll
      for (int j = 0; j < 4; ++j)
        acc[i][j] = __builtin_amdgcn_mfma_f32_16x16x32_bf16(a1[i], bfr2[j], acc[i][j], 0, 0, 0);
    __builtin_amdgcn_s_setprio(0);
    if (kt + 3 < 32) {
#pragma unroll
      for (int i = 0; i < 4; ++i)
        a1[i] = *(const bf16x8*)(gA + (size_t)i * 16 * K + (kt + 3) * 32);
    }
  }

  float biasv[4];
#pragma unroll
  for (int j = 0; j < 4; ++j) biasv[j] = bias[nBase + j * 16 + l16];
#pragma unroll
  for (int i = 0; i < 4; ++i) {
    int gr0 = mBase + wv * 64 + i * 16 + quad * 4;  // C/D: row = quad*4+reg, col = lane&15
#pragma unroll
    for (int j = 0; j < 4; ++j) {
      int col = nBase + j * 16 + l16;
#pragma unroll
      for (int r = 0; r < 4; ++r) {
        int gr = gr0 + r;
        if (gr < M) {
          size_t idx = (size_t)gr * D_DIM + col;
          float v = acc[i][j][r] + biasv[j];
          float rv = __builtin_nontemporal_load(&residual[idx]);
          __builtin_nontemporal_store(fmaxf(v, 0.0f) + rv, &out[idx]);
        }
      }
    }
  }
}

// ---------------- launch ----------------
extern "C" void kernel_launch(void* const* d_in, const int* in_sizes, int n_in,
                              void* d_out, int out_size, void* d_ws, size_t ws_size,
                              hipStream_t stream) {
  const float* x = (const float*)d_in[0];
  const int* ei = (const int*)d_in[1];
  const float* Wl = (const float*)d_in[2];
  const float* bl = (const float*)d_in[3];
  const float* Wr = (const float*)d_in[4];
  const float* gamma = (const float*)d_in[5];
  const float* beta = (const float*)d_in[6];
  float* out = (float*)d_out;

  int n = in_sizes[0] / D_DIM;       // 50000
  int nE = in_sizes[1] / 2;          // 1500000
  const int* src = ei;
  const int* dstv = ei + nE;
  int Mpad = (n + 511) & ~511;       // 50176 (BM=512 tiles)
  int Mtiles = Mpad / 512;           // 98

  char* w = (char*)d_ws;
  size_t off = 0;
  auto carve = [&](size_t bytes) {
    char* p = w + off;
    off += (bytes + 255) & ~(size_t)255;
    return p;
  };
  unsigned short* Acat = (unsigned short*)carve((size_t)Mpad * 1024 * 2);  // 102.8 MB
  unsigned short* Wcat = (unsigned short*)carve((size_t)512 * 1024 * 2);   // 1 MB
  int* sorted = (int*)carve((size_t)nE * 4);                               // 6 MB
  int* cnt = (int*)carve((size_t)n * 4);                                   // also 'cur'
  int* rowst = (int*)carve((size_t)(n + 1) * 4);
  int* bsums = (int*)carve(1024);
  if (off > ws_size) return;  // minimal set doesn't fit -> loud failure

  // fp8 gather copy of h, only if ws allows (+25.6 MB)
  size_t h8_bytes = (size_t)n * 512;
  int use_fp8 = (off + h8_bytes <= ws_size) ? 1 : 0;
  unsigned char* h8 = use_fp8 ? (unsigned char*)carve(h8_bytes) : (unsigned char*)w;

  int nbScan = (n + 1023) / 1024;  // 49 (<=64 required by scan2)

  ln_kernel<<<(n + 3) / 4, 256, 0, stream>>>(x, gamma, beta, Acat, h8, n, use_fp8);
  wconv_kernel<<<(512 * 512) / 256, 256, 0, stream>>>(Wl, Wr, Wcat);
  zero_kernel<<<(n + 255) / 256, 256, 0, stream>>>(cnt, n);
  hist_kernel<<<(nE + 255) / 256, 256, 0, stream>>>(dstv, nE, cnt);
  scan1_kernel<<<nbScan, 1024, 0, stream>>>(cnt, n, rowst, bsums);
  scan2_kernel<<<1, 64, 0, stream>>>(bsums, nbScan);
  scan3_kernel<<<nbScan, 1024, 0, stream>>>(rowst, cnt, bsums, n, nE);  // cur aliases cnt
  scatter_kernel<<<(nE + 255) / 256, 256, 0, stream>>>(src, dstv, nE, cnt, sorted);
  agg_kernel<<<(n + 3) / 4, 256, 0, stream>>>(Acat, h8, rowst, sorted, n, use_fp8);
  // grid: 13 mb-groups x 8 xcd x 8 nb; mb = (b>>6)*8 + (b&7) >= 98 early-exits
  int gemmBlocks = ((Mtiles + 7) / 8) * 64;  // 832
  gemm_kernel<<<gemmBlocks, 512, 0, stream>>>(Acat, Wcat, bl, x, out, n, Mtiles);
}

// Round 8
// 683.018 us; speedup vs baseline: 1.0631x; 1.0631x over previous
//
#include <hip/hip_runtime.h>

// GNN encoder layer: LN -> mean-aggregate over edges -> SAGEConv -> relu -> +residual
// Pipeline (all on `stream`, graph-capture safe):
//  1. ln_kernel      : h = LN(x)*gamma+beta -> bf16 into A_cat[:,512:1024], fp8 copy into h8
//  2. wconv_kernel   : W_cat[j,0:512]=bf16(W_l[j,:]), W_cat[j,512:1024]=bf16(W_r[j,:])
//  3. zero + hist    : cnt[d] = in-degree
//  4. scan1/2/3      : row_start = exclusive_scan(cnt); cur(=cnt) = row_start
//  5. scatter_kernel : sorted_src = src indices grouped by dst (CSR)
//  6. agg_kernel     : mean of fp8 h rows (fp32 accum) -> bf16 into A_cat[:,0:512]
//  7. gemm_kernel    : out = relu(A_cat @ W_cat^T + b_l) + residual
//     Round-10 (full-N blocks, HARDENED): the r6/r7 variant failed the container
//     twice; the only constructs novel vs every kernel that has run were
//     (a) per-lane LDS dest for global_load_lds (implicit readfirstlane) and
//     (b) a builtin s_barrier mixed with asm barriers. Both replaced with the
//     proven idioms: explicit wave-uniform LDS staging bases (+wv*1024) and asm
//     s_barrier. Geometry/hypothesis unchanged: rounds 0-3 showed all barrier-
//     synced schedules deliver staged bytes at ~6 B/cy/CU (L3/HBM streaming
//     wall) -> stage FEWER cold bytes. BM=64 x BN=512 (full width) x BK=32,
//     256 thr, 4 waves x (64x128 out, acc[4][8]): A staged exactly ONCE
//     chip-wide; B (1MB) identical for all blocks -> L2-served. 72KB LDS ->
//     2 blocks/CU. Counted vmcnt(9) dbuf. XOR-4 chunk swizzle both-sides.

#define D_DIM 512

typedef __bf16 bf16x8 __attribute__((ext_vector_type(8)));
typedef float f32x4 __attribute__((ext_vector_type(4)));
typedef float f32x2 __attribute__((ext_vector_type(2)));

__device__ __forceinline__ unsigned short f2bf(float f) {
  unsigned u = __float_as_uint(f);
  u += 0x7fffu + ((u >> 16) & 1u);   // RNE
  return (unsigned short)(u >> 16);
}
__device__ __forceinline__ float bflo(unsigned u) { return __uint_as_float(u << 16); }
__device__ __forceinline__ float bfhi(unsigned u) { return __uint_as_float(u & 0xffff0000u); }
__device__ __forceinline__ unsigned packbf2(float lo, float hi) {
  return (unsigned)f2bf(lo) | ((unsigned)f2bf(hi) << 16);
}

// ---------------- LayerNorm: one wave per row, 8 floats/lane ----------------
__global__ void ln_kernel(const float* __restrict__ x, const float* __restrict__ gamma,
                          const float* __restrict__ beta, unsigned short* __restrict__ Acat,
                          unsigned char* __restrict__ h8, int n, int use_fp8) {
  int lane = threadIdx.x & 63;
  int row = blockIdx.x * 4 + (threadIdx.x >> 6);
  if (row >= n) return;
  const float* xr = x + (size_t)row * D_DIM + lane * 8;
  float4 a = *(const float4*)xr;
  float4 b = *(const float4*)(xr + 4);
  float sum = a.x + a.y + a.z + a.w + b.x + b.y + b.z + b.w;
  float sq = a.x * a.x + a.y * a.y + a.z * a.z + a.w * a.w +
             b.x * b.x + b.y * b.y + b.z * b.z + b.w * b.w;
#pragma unroll
  for (int m = 1; m < 64; m <<= 1) {
    sum += __shfl_xor(sum, m, 64);
    sq  += __shfl_xor(sq, m, 64);
  }
  float mu = sum * (1.0f / D_DIM);
  float var = sq * (1.0f / D_DIM) - mu * mu;
  float rs = rsqrtf(var + 1e-5f);
  const float* gp = gamma + lane * 8;
  const float* bp = beta + lane * 8;
  float4 g0 = *(const float4*)gp, g1 = *(const float4*)(gp + 4);
  float4 e0 = *(const float4*)bp, e1 = *(const float4*)(bp + 4);
  float h0 = (a.x - mu) * rs * g0.x + e0.x;
  float h1 = (a.y - mu) * rs * g0.y + e0.y;
  float h2 = (a.z - mu) * rs * g0.z + e0.z;
  float h3 = (a.w - mu) * rs * g0.w + e0.w;
  float h4 = (b.x - mu) * rs * g1.x + e1.x;
  float h5 = (b.y - mu) * rs * g1.y + e1.y;
  float h6 = (b.z - mu) * rs * g1.z + e1.z;
  float h7 = (b.w - mu) * rs * g1.w + e1.w;
  uint4 st = { packbf2(h0, h1), packbf2(h2, h3), packbf2(h4, h5), packbf2(h6, h7) };
  *(uint4*)(Acat + (size_t)row * 1024 + 512 + lane * 8) = st;
  if (use_fp8) {
    int p0 = __builtin_amdgcn_cvt_pk_fp8_f32(h0, h1, 0, false);
    p0 = __builtin_amdgcn_cvt_pk_fp8_f32(h2, h3, p0, true);
    int p1 = __builtin_amdgcn_cvt_pk_fp8_f32(h4, h5, 0, false);
    p1 = __builtin_amdgcn_cvt_pk_fp8_f32(h6, h7, p1, true);
    uint2 st2 = { (unsigned)p0, (unsigned)p1 };
    *(uint2*)(h8 + (size_t)row * 512 + lane * 8) = st2;
  }
}

// ---------------- W concat + bf16 convert ----------------
__global__ void wconv_kernel(const float* __restrict__ Wl, const float* __restrict__ Wr,
                             unsigned short* __restrict__ Wcat) {
  int id = blockIdx.x * 256 + threadIdx.x;  // 0 .. 512*512-1
  int j = id >> 9, k = id & 511;
  Wcat[(size_t)j * 1024 + k] = f2bf(Wl[id]);
  Wcat[(size_t)j * 1024 + 512 + k] = f2bf(Wr[id]);
}

// ---------------- CSR build ----------------
__global__ void zero_kernel(int* __restrict__ p, int n) {
  int i = blockIdx.x * 256 + threadIdx.x;
  if (i < n) p[i] = 0;
}

__global__ void hist_kernel(const int* __restrict__ dst, int nE, int* __restrict__ cnt) {
  int e = blockIdx.x * 256 + threadIdx.x;
  if (e < nE) atomicAdd(&cnt[dst[e]], 1);
}

__global__ void scan1_kernel(const int* __restrict__ cnt, int n,
                             int* __restrict__ excl, int* __restrict__ bsums) {
  __shared__ int wsum[16];
  int gid = blockIdx.x * 1024 + threadIdx.x;
  int lane = threadIdx.x & 63, wave = threadIdx.x >> 6;
  int v = (gid < n) ? cnt[gid] : 0;
  int s = v;
#pragma unroll
  for (int d = 1; d < 64; d <<= 1) {
    int t = __shfl_up(s, d, 64);
    if (lane >= d) s += t;
  }
  if (lane == 63) wsum[wave] = s;
  __syncthreads();
  if (wave == 0) {
    int ws = (lane < 16) ? wsum[lane] : 0;
#pragma unroll
    for (int d = 1; d < 16; d <<= 1) {
      int t = __shfl_up(ws, d, 64);
      if (lane >= d) ws += t;
    }
    if (lane < 16) wsum[lane] = ws;
  }
  __syncthreads();
  int incl = s + ((wave > 0) ? wsum[wave - 1] : 0);
  if (gid < n) excl[gid] = incl - v;
  if (threadIdx.x == 1023) bsums[blockIdx.x] = incl;
}

__global__ void scan2_kernel(int* __restrict__ bsums, int nb) {
  int lane = threadIdx.x;  // 64 threads, nb <= 64
  int v = (lane < nb) ? bsums[lane] : 0;
  int s = v;
#pragma unroll
  for (int d = 1; d < 64; d <<= 1) {
    int t = __shfl_up(s, d, 64);
    if (lane >= d) s += t;
  }
  if (lane < nb) bsums[lane] = s - v;  // exclusive
}

__global__ void scan3_kernel(int* __restrict__ rowst, int* __restrict__ cur,
                             const int* __restrict__ bsums, int n, int nE) {
  int gid = blockIdx.x * 1024 + threadIdx.x;
  if (gid < n) {
    int r = rowst[gid] + bsums[blockIdx.x];
    rowst[gid] = r;
    cur[gid] = r;
  }
  if (gid == 0) rowst[n] = nE;
}

__global__ void scatter_kernel(const int* __restrict__ src, const int* __restrict__ dst,
                               int nE, int* __restrict__ cur, int* __restrict__ sorted_src) {
  int e = blockIdx.x * 256 + threadIdx.x;
  if (e < nE) {
    int p = atomicAdd(&cur[dst[e]], 1);
    sorted_src[p] = src[e];
  }
}

// ---------------- aggregation: one wave per dst node ----------------
__device__ __forceinline__ void acc_bf(float* acc, uint4 r) {
  acc[0] += bflo(r.x); acc[1] += bfhi(r.x);
  acc[2] += bflo(r.y); acc[3] += bfhi(r.y);
  acc[4] += bflo(r.z); acc[5] += bfhi(r.z);
  acc[6] += bflo(r.w); acc[7] += bfhi(r.w);
}

__device__ __forceinline__ void acc_f8(float* acc, uint2 r) {
  f32x2 a = __builtin_amdgcn_cvt_pk_f32_fp8(r.x, false);
  f32x2 b = __builtin_amdgcn_cvt_pk_f32_fp8(r.x, true);
  f32x2 c = __builtin_amdgcn_cvt_pk_f32_fp8(r.y, false);
  f32x2 d = __builtin_amdgcn_cvt_pk_f32_fp8(r.y, true);
  acc[0] += a.x; acc[1] += a.y; acc[2] += b.x; acc[3] += b.y;
  acc[4] += c.x; acc[5] += c.y; acc[6] += d.x; acc[7] += d.y;
}

__global__ void agg_kernel(unsigned short* __restrict__ Acat,
                           const unsigned char* __restrict__ h8,
                           const int* __restrict__ rowst,
                           const int* __restrict__ sorted_src, int n, int use_fp8) {
  int lane = threadIdx.x & 63;
  int node = blockIdx.x * 4 + (threadIdx.x >> 6);
  if (node >= n) return;
  int s0 = rowst[node], s1 = rowst[node + 1];
  float acc[8] = {0.f, 0.f, 0.f, 0.f, 0.f, 0.f, 0.f, 0.f};
  if (use_fp8) {
    const unsigned char* hb = h8 + lane * 8;
    int e = s0;
    for (; e + 3 < s1; e += 4) {
      int i0 = sorted_src[e], i1 = sorted_src[e + 1];
      int i2 = sorted_src[e + 2], i3 = sorted_src[e + 3];
      uint2 r0 = *(const uint2*)(hb + (size_t)i0 * 512);
      uint2 r1 = *(const uint2*)(hb + (size_t)i1 * 512);
      uint2 r2 = *(const uint2*)(hb + (size_t)i2 * 512);
      uint2 r3 = *(const uint2*)(hb + (size_t)i3 * 512);
      acc_f8(acc, r0); acc_f8(acc, r1); acc_f8(acc, r2); acc_f8(acc, r3);
    }
    for (; e < s1; ++e) {
      uint2 r0 = *(const uint2*)(hb + (size_t)sorted_src[e] * 512);
      acc_f8(acc, r0);
    }
  } else {
    const unsigned short* hbase = Acat + 512 + lane * 8;
    int e = s0;
    for (; e + 3 < s1; e += 4) {
      int i0 = sorted_src[e], i1 = sorted_src[e + 1];
      int i2 = sorted_src[e + 2], i3 = sorted_src[e + 3];
      uint4 r0 = *(const uint4*)(hbase + (size_t)i0 * 1024);
      uint4 r1 = *(const uint4*)(hbase + (size_t)i1 * 1024);
      uint4 r2 = *(const uint4*)(hbase + (size_t)i2 * 1024);
      uint4 r3 = *(const uint4*)(hbase + (size_t)i3 * 1024);
      acc_bf(acc, r0); acc_bf(acc, r1); acc_bf(acc, r2); acc_bf(acc, r3);
    }
    for (; e < s1; ++e) {
      uint4 r0 = *(const uint4*)(hbase + (size_t)sorted_src[e] * 1024);
      acc_bf(acc, r0);
    }
  }
  int deg = s1 - s0;
  float sc = (deg > 0) ? (1.0f / (float)deg) : 0.0f;
  uint4 st = { packbf2(acc[0] * sc, acc[1] * sc), packbf2(acc[2] * sc, acc[3] * sc),
               packbf2(acc[4] * sc, acc[5] * sc), packbf2(acc[6] * sc, acc[7] * sc) };
  *(uint4*)(Acat + (size_t)node * 1024 + lane * 8) = st;
}

// ---------------- GEMM: [Mpad x 1024] @ [512 x 1024]^T, full-N blocks ----------------
// BM=64 x BN=512 x BK=32, 256 thr (4 waves; wave = 64 rows x 128 cols, acc[4][8]).
// A staged once chip-wide; B (1MB) identical for all blocks -> L2-served.
// LDS: 2 x (4KB A + 32KB B) = 72KB -> 2 blocks/CU. Counted vmcnt(9) dbuf.
// Staging uses EXPLICIT wave-uniform LDS bases (guide m104: DMA dest is
// wave-uniform base + lane*16); per-lane global sources carry the swizzle.
// XOR-4 swizzle: LDS slot (row, d) holds global 16B-chunk d ^ (row&3), applied
// on BOTH the pre-swizzled DMA source and the ds_read index (rule #21).
__device__ __forceinline__ void async16(const unsigned short* g, char* lds) {
  __builtin_amdgcn_global_load_lds((const __attribute__((address_space(1))) void*)g,
                                   (__attribute__((address_space(3))) void*)lds, 16, 0, 0);
}

__global__ __launch_bounds__(256, 2) void gemm_kernel(
    const unsigned short* __restrict__ A,  // [Mpad][1024] bf16 (mean | h)
    const unsigned short* __restrict__ B,  // [512][1024]  bf16 (W_l | W_r), row = out col
    const float* __restrict__ bias,        // b_l [512]
    const float* __restrict__ residual,    // x [M][512]
    float* __restrict__ out, int M) {
  __shared__ unsigned short sA[2][64 * 32];   // 2 x 4 KB
  __shared__ unsigned short sB[2][512 * 32];  // 2 x 32 KB
  const int K = 1024;
  int t = threadIdx.x;
  int lane = t & 63;
  int quad = lane >> 4, l16 = lane & 15;
  int wv = t >> 6;            // 4 waves
  int mBase = blockIdx.x * 64;
  int wn = wv * 128;          // wave's 128 output cols

  // staging: thread t covers LDS slot (row = t>>2 [+64*ib for B], chunk d = t&3);
  // source chunk = d ^ (row&3) = (t&3) ^ ((t>>2)&3)  (sub-tile row bases %4==0).
  // DMA writes base+lane*16 with wave-uniform base = wv*1024 (+ib*4096 for B).
  int srow = t >> 2;
  int schunk = ((t & 3) ^ ((t >> 2) & 3)) * 8;  // shorts
  const unsigned short* gA = A + (size_t)(mBase + srow) * K + schunk;
  const unsigned short* gB = B + (size_t)srow * K + schunk;

  f32x4 acc[4][8] = {};

  auto stage = [&](int buf, int kt) {
    int kOff = kt << 5;  // kt*32 shorts
    char* la = (char*)&sA[buf][0] + wv * 1024;   // wave-uniform dest base
    char* lb = (char*)&sB[buf][0] + wv * 1024;
    async16(gA + kOff, la);
#pragma unroll
    for (int ib = 0; ib < 8; ++ib)
      async16(gB + (size_t)ib * 64 * K + kOff, lb + ib * 4096);
  };

  int swz = l16 & 3;  // fragment rows differ only in l16; row&3 == l16&3
  auto compute = [&](int buf) {
    bf16x8 af[4], bfr[8];
#pragma unroll
    for (int i = 0; i < 4; ++i)
      af[i] = *(const bf16x8*)(&sA[buf][(i * 16 + l16) * 32 + ((quad ^ swz) * 8)]);
#pragma unroll
    for (int j = 0; j < 8; ++j)
      bfr[j] = *(const bf16x8*)(&sB[buf][(wn + j * 16 + l16) * 32 + ((quad ^ swz) * 8)]);
    __builtin_amdgcn_s_setprio(1);
#pragma unroll
    for (int i = 0; i < 4; ++i)
#pragma unroll
      for (int j = 0; j < 8; ++j)
        acc[i][j] = __builtin_amdgcn_mfma_f32_16x16x32_bf16(af[i], bfr[j], acc[i][j], 0, 0, 0);
    __builtin_amdgcn_s_setprio(0);
  };

  // prologue: tiles 0,1 staged (18 loads/thread outstanding)
  stage(0, 0);
  stage(1, 1);
  // steady state: vmcnt(9) -> tile kt landed, tile kt+1's 9 stay in flight;
  // barrier 1 = whole tile visible block-wide; barrier 2 (no wait) = all waves
  // done reading buf before it is re-staged with tile kt+2.
  for (int kt = 0; kt < 30; ++kt) {
    asm volatile("s_waitcnt vmcnt(9)\n\ts_barrier" ::: "memory");
    compute(kt & 1);
    asm volatile("s_barrier" ::: "memory");
    stage(kt & 1, kt + 2);
  }
  asm volatile("s_waitcnt vmcnt(9)\n\ts_barrier" ::: "memory");
  compute(0);  // kt=30 (staged into buf 0 at kt=28)
  asm volatile("s_waitcnt vmcnt(0)\n\ts_barrier" ::: "memory");
  compute(1);  // kt=31 (staged into buf 1 at kt=29)

  float biasv[8];
#pragma unroll
  for (int j = 0; j < 8; ++j) biasv[j] = bias[wn + j * 16 + l16];
#pragma unroll
  for (int i = 0; i < 4; ++i) {
    int gr0 = mBase + i * 16 + quad * 4;  // C/D: row = quad*4+reg, col = lane&15
#pragma unroll
    for (int j = 0; j < 8; ++j) {
      int col = wn + j * 16 + l16;
#pragma unroll
      for (int r = 0; r < 4; ++r) {
        int gr = gr0 + r;
        if (gr < M) {
          size_t idx = (size_t)gr * D_DIM + col;
          float v = acc[i][j][r] + biasv[j];
          float rv = __builtin_nontemporal_load(&residual[idx]);
          __builtin_nontemporal_store(fmaxf(v, 0.0f) + rv, &out[idx]);
        }
      }
    }
  }
}

// ---------------- launch ----------------
extern "C" void kernel_launch(void* const* d_in, const int* in_sizes, int n_in,
                              void* d_out, int out_size, void* d_ws, size_t ws_size,
                              hipStream_t stream) {
  const float* x = (const float*)d_in[0];
  const int* ei = (const int*)d_in[1];
  const float* Wl = (const float*)d_in[2];
  const float* bl = (const float*)d_in[3];
  const float* Wr = (const float*)d_in[4];
  const float* gamma = (const float*)d_in[5];
  const float* beta = (const float*)d_in[6];
  float* out = (float*)d_out;

  int n = in_sizes[0] / D_DIM;       // 50000
  int nE = in_sizes[1] / 2;          // 1500000
  const int* src = ei;
  const int* dstv = ei + nE;
  int Mpad = (n + 63) & ~63;         // 50048 (BM=64 tiles)
  int Mtiles = Mpad / 64;            // 782

  char* w = (char*)d_ws;
  size_t off = 0;
  auto carve = [&](size_t bytes) {
    char* p = w + off;
    off += (bytes + 255) & ~(size_t)255;
    return p;
  };
  unsigned short* Acat = (unsigned short*)carve((size_t)Mpad * 1024 * 2);  // 102.5 MB
  unsigned short* Wcat = (unsigned short*)carve((size_t)512 * 1024 * 2);   // 1 MB
  int* sorted = (int*)carve((size_t)nE * 4);                               // 6 MB
  int* cnt = (int*)carve((size_t)n * 4);                                   // also 'cur'
  int* rowst = (int*)carve((size_t)(n + 1) * 4);
  int* bsums = (int*)carve(1024);
  if (off > ws_size) return;  // minimal set doesn't fit -> loud failure

  // fp8 gather copy of h, only if ws allows (+25.6 MB)
  size_t h8_bytes = (size_t)n * 512;
  int use_fp8 = (off + h8_bytes <= ws_size) ? 1 : 0;
  unsigned char* h8 = use_fp8 ? (unsigned char*)carve(h8_bytes) : (unsigned char*)w;

  int nbScan = (n + 1023) / 1024;  // 49 (<=64 required by scan2)

  ln_kernel<<<(n + 3) / 4, 256, 0, stream>>>(x, gamma, beta, Acat, h8, n, use_fp8);
  wconv_kernel<<<(512 * 512) / 256, 256, 0, stream>>>(Wl, Wr, Wcat);
  zero_kernel<<<(n + 255) / 256, 256, 0, stream>>>(cnt, n);
  hist_kernel<<<(nE + 255) / 256, 256, 0, stream>>>(dstv, nE, cnt);
  scan1_kernel<<<nbScan, 1024, 0, stream>>>(cnt, n, rowst, bsums);
  scan2_kernel<<<1, 64, 0, stream>>>(bsums, nbScan);
  scan3_kernel<<<nbScan, 1024, 0, stream>>>(rowst, cnt, bsums, n, nE);  // cur aliases cnt
  scatter_kernel<<<(nE + 255) / 256, 256, 0, stream>>>(src, dstv, nE, cnt, sorted);
  agg_kernel<<<(n + 3) / 4, 256, 0, stream>>>(Acat, h8, rowst, sorted, n, use_fp8);
  // one block per 64-row stripe; every block computes the full 512 output cols
  gemm_kernel<<<Mtiles, 256, 0, stream>>>(Acat, Wcat, bl, x, out, n);
}